// Round 7
// baseline (227.026 us; speedup 1.0000x reference)
//
#include <hip/hip_runtime.h>

// Problem constants: B=2, S=2048, D=1024, H=16, HD=64, M = B*S = 4096

typedef __bf16 bf16;
typedef bf16  bf16x8 __attribute__((ext_vector_type(8)));
typedef bf16  bf16x4 __attribute__((ext_vector_type(4)));
typedef float f32x4  __attribute__((ext_vector_type(4)));
typedef float f32x16 __attribute__((ext_vector_type(16)));

typedef const __attribute__((address_space(1))) void* gptr_t;
typedef __attribute__((address_space(3))) void*       sptr_t;

__device__ __forceinline__ void gload_lds16(const void* g, void* l) {
  __builtin_amdgcn_global_load_lds((gptr_t)g, (sptr_t)l, 16, 0, 0);
}

__device__ __forceinline__ float fexp2(float x) {  // raw v_exp_f32 (2^x)
  float r; asm("v_exp_f32 %0, %1" : "=v"(r) : "v"(x)); return r;
}
__device__ __forceinline__ float max3f(float a, float b, float c) {
  float r; asm("v_max3_f32 %0, %1, %2, %3" : "=v"(r) : "v"(a), "v"(b), "v"(c));
  return r;
}
__device__ __forceinline__ unsigned pkbf(float a, float b) {  // lo=a, hi=b
  unsigned r;
  asm("v_cvt_pk_bf16_f32 %0, %1, %2" : "=v"(r) : "v"(a), "v"(b));
  return r;
}

// ------------------------------------------------- fused prep: f2bf x4 + rope
__global__ __launch_bounds__(256) void prep_kernel(
    const float* __restrict__ x, const float* __restrict__ wq,
    const float* __restrict__ wk, const float* __restrict__ wv,
    bf16* __restrict__ xb, bf16* __restrict__ wqb, bf16* __restrict__ wkb,
    bf16* __restrict__ wvb, float* __restrict__ ctab, float* __restrict__ stab) {
  int g = blockIdx.x * 256 + threadIdx.x;
  const float* src;
  bf16* dst;
  int i;
  if (g < 1048576) { src = x; dst = xb; i = g; }
  else if (g < 1310720) { src = wq; dst = wqb; i = g - 1048576; }
  else if (g < 1572864) { src = wk; dst = wkb; i = g - 1310720; }
  else if (g < 1835008) { src = wv; dst = wvb; i = g - 1572864; }
  else {
    int idx = g - 1835008;
    if (idx < 65536) {
      int s = idx >> 5, p = idx & 31;
      double theta = exp2(-(double)p * (13.287712379549449 / 32.0));
      double ang = (double)s * theta;
      ctab[idx] = (float)cos(ang);
      stab[idx] = (float)sin(ang);
    }
    return;
  }
  const float4 v = reinterpret_cast<const float4*>(src)[i];
  bf16x4 o;
  o[0] = (bf16)v.x; o[1] = (bf16)v.y; o[2] = (bf16)v.z; o[3] = (bf16)v.w;
  reinterpret_cast<bf16x4*>(dst)[i] = o;
}

// ---------------------------------------------------------------- QKV GEMM
// BK=64, T2 XOR-swizzled LDS (both-sides), fused RoPE epilogue; z==2 writes
// V directly transposed into vt[bh][d][s].
__global__ __launch_bounds__(256) void qkv_gemm_kernel(
    const bf16* __restrict__ xb, const bf16* __restrict__ wqb,
    const bf16* __restrict__ wkb, const bf16* __restrict__ wvb,
    const float* __restrict__ bq, const float* __restrict__ bk2,
    const float* __restrict__ bv, const float* __restrict__ ctab,
    const float* __restrict__ stab, bf16* __restrict__ qb,
    bf16* __restrict__ kb, bf16* __restrict__ vt) {
  const int z = blockIdx.z;
  const bf16* W = (z == 0) ? wqb : (z == 1) ? wkb : wvb;
  const float* bias = (z == 0) ? bq : (z == 1) ? bk2 : bv;

  __shared__ bf16 As[128 * 64];
  __shared__ bf16 Bs[128 * 64];

  const int tid = threadIdx.x;
  const int wid = tid >> 6;
  const int l = tid & 63;
  const int lg = l >> 4, lc = l & 15;
  const int wr = wid >> 1, wc = wid & 1;
  const int m0 = blockIdx.x * 128, n0 = blockIdx.y * 128;

  f32x4 acc[4][4] = {};

  // staging: thread covers row 32*i + srow, source chunk pre-swizzled
  const int srow = tid >> 3;                    // 0..31
  const int schunk = (tid & 7) ^ (srow & 7);    // 16B chunks, 8 per 64-col row
  const bf16* asrc = xb + (size_t)(m0 + srow) * 1024 + schunk * 8;
  const bf16* bsrc = W + (size_t)(n0 + srow) * 1024 + schunk * 8;
  char* alds = (char*)As + wid * 1024;
  char* blds = (char*)Bs + wid * 1024;

  for (int k0 = 0; k0 < 1024; k0 += 64) {
#pragma unroll
    for (int i = 0; i < 4; ++i) {
      gload_lds16(asrc + (size_t)32 * i * 1024 + k0, alds + i * 4096);
      gload_lds16(bsrc + (size_t)32 * i * 1024 + k0, blds + i * 4096);
    }
    __syncthreads();
    bf16x8 af[4][2], bfr[4][2];
#pragma unroll
    for (int i = 0; i < 4; ++i) {
      const int row = wr * 64 + i * 16 + lc;
#pragma unroll
      for (int h = 0; h < 2; ++h) {
        const int slot = (h * 4 + lg) ^ (row & 7);
        af[i][h] = *reinterpret_cast<const bf16x8*>(
            (const char*)As + row * 128 + slot * 16);
      }
    }
#pragma unroll
    for (int j = 0; j < 4; ++j) {
      const int row = wc * 64 + j * 16 + lc;
#pragma unroll
      for (int h = 0; h < 2; ++h) {
        const int slot = (h * 4 + lg) ^ (row & 7);
        bfr[j][h] = *reinterpret_cast<const bf16x8*>(
            (const char*)Bs + row * 128 + slot * 16);
      }
    }
    __builtin_amdgcn_s_setprio(1);
#pragma unroll
    for (int i = 0; i < 4; ++i)
#pragma unroll
      for (int j = 0; j < 4; ++j) {
        acc[i][j] = __builtin_amdgcn_mfma_f32_16x16x32_bf16(af[i][0], bfr[j][0],
                                                            acc[i][j], 0, 0, 0);
        acc[i][j] = __builtin_amdgcn_mfma_f32_16x16x32_bf16(af[i][1], bfr[j][1],
                                                            acc[i][j], 0, 0, 0);
      }
    __builtin_amdgcn_s_setprio(0);
    __syncthreads();
  }

#pragma unroll
  for (int i = 0; i < 4; ++i)
#pragma unroll
    for (int j = 0; j < 4; ++j) {
      const int nb = n0 + wc * 64 + j * 16 + lc;
      const float bval = bias[nb];
#pragma unroll
      for (int r = 0; r < 4; ++r) {
        const int m = m0 + wr * 64 + i * 16 + lg * 4 + r;
        const float val = acc[i][j][r] + bval;
        if (z == 2) {
          // vt[bh][d][s], bh = (m>>11)*16 + (nb>>6), d = nb&63, s = m&2047
          vt[((size_t)((m >> 11) * 16 + (nb >> 6)) * 64 + (nb & 63)) * 2048 +
             (m & 2047)] = (bf16)val;
        } else {
          const int s = m & 2047;
          const int pi = (nb & 63) >> 1;
          const float c = ctab[s * 32 + pi];
          const float sn = stab[s * 32 + pi];
          const float part = __shfl_xor(val, 1, 64);
          float res = (nb & 1) ? fmaf(part, sn, val * c)
                               : fmaf(-part, sn, val * c);
          if (z == 0) res *= 0.18033688011112042f;  // (1/8) * log2(e)
          bf16* dst = (z == 0) ? qb : kb;
          dst[(size_t)m * 1024 + nb] = (bf16)res;
        }
      }
    }
}

// ---------------------------------------------------------------- Attention v6
// 2 waves x 32 q-rows (64 q/block), K/V LDS-staged (KVBLK=64, dbuf, XOR
// swizzle both-sides). Swapped QK^T (32x32x16), in-register online softmax
// (exp2 domain, raw v_exp). Cross-half moves via PROVEN __shfl_xor(.,32).
__global__ __launch_bounds__(128) void attn_kernel(const bf16* __restrict__ qb,
                                                   const bf16* __restrict__ kb,
                                                   const bf16* __restrict__ vt,
                                                   float* __restrict__ out) {
  __shared__ bf16 Kt[2][64][64];
  __shared__ bf16 Vt[2][64][64];

  const int tid = threadIdx.x;
  const int wid = tid >> 6;
  const int l = tid & 63;
  const int lc = l & 31;      // q index within tile (MFMA C col)
  const int hi = l >> 5;      // half-wave
  // XCD swizzle over 1024 blocks -> same-head blocks colocate per XCD
  const int bid = blockIdx.x;
  const int swz = (bid & 7) * 128 + (bid >> 3);
  const int bh = swz >> 5;          // 0..31
  const int qt = swz & 31;          // 0..31
  const int b = bh >> 4, h = bh & 15;
  const int q0 = qt * 64 + wid * 32;

  const bf16* Q = qb + (size_t)(b * 2048 + q0) * 1024 + h * 64;
  const bf16* K = kb + (size_t)(b * 2048) * 1024 + h * 64;
  const bf16* V = vt + (size_t)bh * 64 * 2048;

  // Q fragment (B-operand of QK^T): qf[md][t] = Q[q0+lc][md*16 + hi*8 + t]
  bf16x8 qf[4];
#pragma unroll
  for (int md = 0; md < 4; ++md)
    qf[md] = *reinterpret_cast<const bf16x8*>(Q + (size_t)lc * 1024 + md * 16 + hi * 8);

  // Staging: wave stages K rows [wid*32, wid*32+32) and V rows same
  const int srow = l >> 3;                  // 0..7
  const int schk = (l & 7) ^ (srow & 7);    // pre-swizzled source chunk
  const bf16* ksrc = K + (size_t)(wid * 32 + srow) * 1024 + schk * 8;
  const bf16* vsrc = V + (size_t)(wid * 32 + srow) * 2048 + schk * 8;

  f32x16 o0 = {};  // O^T rows d = 0..31  (d = (r&3)+8*(r>>2)+4*hi)
  f32x16 o1 = {};  // O^T rows d = 32..63
  float mrun = -1e30f, lrun = 0.f;
  const int sb = (hi ^ 1) * 2;  // exchange pre-select base (PROVEN R4 form)
  const int swzk = lc & 7;      // read-side XOR key

  // prologue: stage tile 0 into buffer 0
#pragma unroll
  for (int j = 0; j < 4; ++j) {
    gload_lds16(ksrc + (size_t)8 * j * 1024, &Kt[0][wid * 32 + 8 * j][0]);
    gload_lds16(vsrc + (size_t)8 * j * 2048, &Vt[0][wid * 32 + 8 * j][0]);
  }
  __syncthreads();

  int bb = 0;
  for (int kt0 = 0; kt0 < 32; ++kt0) {
    if (kt0 < 31) {
      const size_t ko = (size_t)(kt0 + 1) * 64 * 1024;
      const size_t vo = (size_t)(kt0 + 1) * 64;
#pragma unroll
      for (int j = 0; j < 4; ++j) {
        gload_lds16(ksrc + ko + (size_t)8 * j * 1024,
                    &Kt[bb ^ 1][wid * 32 + 8 * j][0]);
        gload_lds16(vsrc + vo + (size_t)8 * j * 2048,
                    &Vt[bb ^ 1][wid * 32 + 8 * j][0]);
      }
    }
#pragma unroll
    for (int sub = 0; sub < 2; ++sub) {
      // ---- S^T tile [32 k][32 q]: A = K rows (LDS), B = Q
      f32x16 s = {};
      __builtin_amdgcn_s_setprio(1);
#pragma unroll
      for (int md = 0; md < 4; ++md) {
        bf16x8 kf = *reinterpret_cast<const bf16x8*>(
            &Kt[bb][sub * 32 + lc][(((md << 1) | hi) ^ swzk) << 3]);
        s = __builtin_amdgcn_mfma_f32_32x32x16_bf16(kf, qf[md], s, 0, 0, 0);
      }
      __builtin_amdgcn_s_setprio(0);

      // ---- online softmax (exp2 domain), in-register
      float t0 = max3f(s[0], s[1], s[2]);
      float t1 = max3f(s[3], s[4], s[5]);
      float t2 = max3f(s[6], s[7], s[8]);
      float t3 = max3f(s[9], s[10], s[11]);
      float t4 = max3f(s[12], s[13], s[14]);
      float tm = fmaxf(max3f(t0, t1, t2), max3f(t3, t4, s[15]));
      tm = fmaxf(tm, __shfl_xor(tm, 32, 64));
      if (!__all(tm <= mrun + 8.0f)) {   // T13 defer-max
        const float mn = fmaxf(mrun, tm);
        const float corr = fexp2(mrun - mn);
        mrun = mn;
        lrun *= corr;
#pragma unroll
        for (int r = 0; r < 16; ++r) { o0[r] *= corr; o1[r] *= corr; }
      }
      float ts = 0.f;
#pragma unroll
      for (int r = 0; r < 16; ++r) {
        s[r] = fexp2(s[r] - mrun);
        ts += s[r];
      }
      ts += __shfl_xor(ts, 32, 64);
      lrun += ts;

      // ---- pack P^T to bf16 pairs; exchange halves (R4-proven sb-trick)
      unsigned pw[8];
#pragma unroll
      for (int w = 0; w < 8; ++w) pw[w] = pkbf(s[2 * w], s[2 * w + 1]);

      unsigned rx0 = __shfl_xor(pw[sb + 0], 32, 64);
      unsigned rx1 = __shfl_xor(pw[sb + 1], 32, 64);
      unsigned rx2 = __shfl_xor(pw[4 + sb + 0], 32, 64);
      unsigned rx3 = __shfl_xor(pw[4 + sb + 1], 32, 64);

      union { unsigned u[4]; bf16x8 v; } bf0, bf1;
      if (hi == 0) {
        bf0.u[0] = pw[0]; bf0.u[1] = pw[1]; bf0.u[2] = rx0; bf0.u[3] = rx1;
        bf1.u[0] = pw[4]; bf1.u[1] = pw[5]; bf1.u[2] = rx2; bf1.u[3] = rx3;
      } else {
        bf0.u[0] = rx0; bf0.u[1] = rx1; bf0.u[2] = pw[2]; bf0.u[3] = pw[3];
        bf1.u[0] = rx2; bf1.u[1] = rx3; bf1.u[2] = pw[6]; bf1.u[3] = pw[7];
      }

      // ---- PV: A = V^T rows (LDS), k = 16 per MFMA
      const int vc = sub * 4 + hi;
      bf16x8 vf00 = *reinterpret_cast<const bf16x8*>(
          &Vt[bb][lc][((vc ^ swzk)) << 3]);
      bf16x8 vf01 = *reinterpret_cast<const bf16x8*>(
          &Vt[bb][lc][(((vc + 2) ^ swzk)) << 3]);
      bf16x8 vf10 = *reinterpret_cast<const bf16x8*>(
          &Vt[bb][lc + 32][((vc ^ swzk)) << 3]);
      bf16x8 vf11 = *reinterpret_cast<const bf16x8*>(
          &Vt[bb][lc + 32][(((vc + 2) ^ swzk)) << 3]);
      __builtin_amdgcn_s_setprio(1);
      o0 = __builtin_amdgcn_mfma_f32_32x32x16_bf16(vf00, bf0.v, o0, 0, 0, 0);
      o0 = __builtin_amdgcn_mfma_f32_32x32x16_bf16(vf01, bf1.v, o0, 0, 0, 0);
      o1 = __builtin_amdgcn_mfma_f32_32x32x16_bf16(vf10, bf0.v, o1, 0, 0, 0);
      o1 = __builtin_amdgcn_mfma_f32_32x32x16_bf16(vf11, bf1.v, o1, 0, 0, 0);
      __builtin_amdgcn_s_setprio(0);
    }
    __syncthreads();
    bb ^= 1;
  }

  // ---- epilogue: out[b][q][h*64+d] = O^T[d][q] / lrun, f32x4 stores
  const float inv = 1.f / lrun;
  float* orow = out + (size_t)(b * 2048 + q0 + lc) * 1024 + h * 64;
#pragma unroll
  for (int g = 0; g < 4; ++g) {
    f32x4 v0, v1;
#pragma unroll
    for (int e = 0; e < 4; ++e) { v0[e] = o0[g * 4 + e] * inv; v1[e] = o1[g * 4 + e] * inv; }
    *reinterpret_cast<f32x4*>(orow + g * 8 + 4 * hi) = v0;
    *reinterpret_cast<f32x4*>(orow + 32 + g * 8 + 4 * hi) = v1;
  }
}

// ---------------------------------------------------------------- launch
extern "C" void kernel_launch(void* const* d_in, const int* in_sizes, int n_in,
                              void* d_out, int out_size, void* d_ws, size_t ws_size,
                              hipStream_t stream) {
  const float* x  = (const float*)d_in[0];
  const float* wq = (const float*)d_in[1];
  const float* bq = (const float*)d_in[2];
  const float* wk = (const float*)d_in[3];
  const float* bk = (const float*)d_in[4];
  const float* wv = (const float*)d_in[5];
  const float* bv = (const float*)d_in[6];
  float* out = (float*)d_out;

  char* ws = (char*)d_ws;
  bf16* xb  = (bf16*)(ws);                    // 8,388,608 B
  bf16* wqb = (bf16*)(ws + 8388608);          // 2,097,152
  bf16* wkb = (bf16*)(ws + 10485760);         // 2,097,152
  bf16* wvb = (bf16*)(ws + 12582912);         // 2,097,152
  bf16* qb  = (bf16*)(ws + 14680064);         // 8,388,608
  bf16* kb  = (bf16*)(ws + 23068672);         // 8,388,608
  bf16* vt  = (bf16*)(ws + 31457280);         // 8,388,608
  float* ctab = (float*)(ws + 39845888);      // 262,144
  float* stab = (float*)(ws + 40108032);      // 262,144

  prep_kernel<<<7424, 256, 0, stream>>>(x, wq, wk, wv, xb, wqb, wkb, wvb,
                                        ctab, stab);

  qkv_gemm_kernel<<<dim3(32, 8, 3), 256, 0, stream>>>(
      xb, wqb, wkb, wvb, bq, bk, bv, ctab, stab, qb, kb, vt);

  attn_kernel<<<1024, 128, 0, stream>>>(qb, kb, vt, out);
}

// Round 8
// 213.537 us; speedup vs baseline: 1.0632x; 1.0632x over previous
//
#include <hip/hip_runtime.h>

// Problem constants: B=2, S=2048, D=1024, H=16, HD=64, M = B*S = 4096

typedef __bf16 bf16;
typedef bf16  bf16x8 __attribute__((ext_vector_type(8)));
typedef bf16  bf16x4 __attribute__((ext_vector_type(4)));
typedef float f32x4  __attribute__((ext_vector_type(4)));
typedef float f32x16 __attribute__((ext_vector_type(16)));

typedef const __attribute__((address_space(1))) void* gptr_t;
typedef __attribute__((address_space(3))) void*       sptr_t;

__device__ __forceinline__ void gload_lds16(const void* g, void* l) {
  __builtin_amdgcn_global_load_lds((gptr_t)g, (sptr_t)l, 16, 0, 0);
}

__device__ __forceinline__ float fexp2(float x) {  // raw v_exp_f32 (2^x)
  float r; asm("v_exp_f32 %0, %1" : "=v"(r) : "v"(x)); return r;
}
__device__ __forceinline__ float max3f(float a, float b, float c) {
  float r; asm("v_max3_f32 %0, %1, %2, %3" : "=v"(r) : "v"(a), "v"(b), "v"(c));
  return r;
}
__device__ __forceinline__ unsigned pkbf(float a, float b) {  // lo=a, hi=b
  unsigned r;
  asm("v_cvt_pk_bf16_f32 %0, %1, %2" : "=v"(r) : "v"(a), "v"(b));
  return r;
}

// ------------------------------------------------- fused prep: f2bf x4 + rope
__global__ __launch_bounds__(256) void prep_kernel(
    const float* __restrict__ x, const float* __restrict__ wq,
    const float* __restrict__ wk, const float* __restrict__ wv,
    bf16* __restrict__ xb, bf16* __restrict__ wqb, bf16* __restrict__ wkb,
    bf16* __restrict__ wvb, float* __restrict__ ctab, float* __restrict__ stab) {
  int g = blockIdx.x * 256 + threadIdx.x;
  const float* src;
  bf16* dst;
  int i;
  if (g < 1048576) { src = x; dst = xb; i = g; }
  else if (g < 1310720) { src = wq; dst = wqb; i = g - 1048576; }
  else if (g < 1572864) { src = wk; dst = wkb; i = g - 1310720; }
  else if (g < 1835008) { src = wv; dst = wvb; i = g - 1572864; }
  else {
    int idx = g - 1835008;
    if (idx < 65536) {
      int s = idx >> 5, p = idx & 31;
      double theta = exp2(-(double)p * (13.287712379549449 / 32.0));
      double ang = (double)s * theta;
      ctab[idx] = (float)cos(ang);
      stab[idx] = (float)sin(ang);
    }
    return;
  }
  const float4 v = reinterpret_cast<const float4*>(src)[i];
  bf16x4 o;
  o[0] = (bf16)v.x; o[1] = (bf16)v.y; o[2] = (bf16)v.z; o[3] = (bf16)v.w;
  reinterpret_cast<bf16x4*>(dst)[i] = o;
}

// ---------------------------------------------------------------- QKV GEMM
// BK=64, T2 XOR-swizzled LDS (both-sides), fused RoPE epilogue; z==2 writes
// V directly transposed into vt[bh][d][s].
__global__ __launch_bounds__(256) void qkv_gemm_kernel(
    const bf16* __restrict__ xb, const bf16* __restrict__ wqb,
    const bf16* __restrict__ wkb, const bf16* __restrict__ wvb,
    const float* __restrict__ bq, const float* __restrict__ bk2,
    const float* __restrict__ bv, const float* __restrict__ ctab,
    const float* __restrict__ stab, bf16* __restrict__ qb,
    bf16* __restrict__ kb, bf16* __restrict__ vt) {
  const int z = blockIdx.z;
  const bf16* W = (z == 0) ? wqb : (z == 1) ? wkb : wvb;
  const float* bias = (z == 0) ? bq : (z == 1) ? bk2 : bv;

  __shared__ bf16 As[128 * 64];
  __shared__ bf16 Bs[128 * 64];

  const int tid = threadIdx.x;
  const int wid = tid >> 6;
  const int l = tid & 63;
  const int lg = l >> 4, lc = l & 15;
  const int wr = wid >> 1, wc = wid & 1;
  const int m0 = blockIdx.x * 128, n0 = blockIdx.y * 128;

  f32x4 acc[4][4] = {};

  // staging: thread covers row 32*i + srow, source chunk pre-swizzled
  const int srow = tid >> 3;                    // 0..31
  const int schunk = (tid & 7) ^ (srow & 7);    // 16B chunks, 8 per 64-col row
  const bf16* asrc = xb + (size_t)(m0 + srow) * 1024 + schunk * 8;
  const bf16* bsrc = W + (size_t)(n0 + srow) * 1024 + schunk * 8;
  char* alds = (char*)As + wid * 1024;
  char* blds = (char*)Bs + wid * 1024;

  for (int k0 = 0; k0 < 1024; k0 += 64) {
#pragma unroll
    for (int i = 0; i < 4; ++i) {
      gload_lds16(asrc + (size_t)32 * i * 1024 + k0, alds + i * 4096);
      gload_lds16(bsrc + (size_t)32 * i * 1024 + k0, blds + i * 4096);
    }
    __syncthreads();
    bf16x8 af[4][2], bfr[4][2];
#pragma unroll
    for (int i = 0; i < 4; ++i) {
      const int row = wr * 64 + i * 16 + lc;
#pragma unroll
      for (int h = 0; h < 2; ++h) {
        const int slot = (h * 4 + lg) ^ (row & 7);
        af[i][h] = *reinterpret_cast<const bf16x8*>(
            (const char*)As + row * 128 + slot * 16);
      }
    }
#pragma unroll
    for (int j = 0; j < 4; ++j) {
      const int row = wc * 64 + j * 16 + lc;
#pragma unroll
      for (int h = 0; h < 2; ++h) {
        const int slot = (h * 4 + lg) ^ (row & 7);
        bfr[j][h] = *reinterpret_cast<const bf16x8*>(
            (const char*)Bs + row * 128 + slot * 16);
      }
    }
    __builtin_amdgcn_s_setprio(1);
#pragma unroll
    for (int i = 0; i < 4; ++i)
#pragma unroll
      for (int j = 0; j < 4; ++j) {
        acc[i][j] = __builtin_amdgcn_mfma_f32_16x16x32_bf16(af[i][0], bfr[j][0],
                                                            acc[i][j], 0, 0, 0);
        acc[i][j] = __builtin_amdgcn_mfma_f32_16x16x32_bf16(af[i][1], bfr[j][1],
                                                            acc[i][j], 0, 0, 0);
      }
    __builtin_amdgcn_s_setprio(0);
    __syncthreads();
  }

#pragma unroll
  for (int i = 0; i < 4; ++i)
#pragma unroll
    for (int j = 0; j < 4; ++j) {
      const int nb = n0 + wc * 64 + j * 16 + lc;
      const float bval = bias[nb];
#pragma unroll
      for (int r = 0; r < 4; ++r) {
        const int m = m0 + wr * 64 + i * 16 + lg * 4 + r;
        const float val = acc[i][j][r] + bval;
        if (z == 2) {
          // vt[bh][d][s], bh = (m>>11)*16 + (nb>>6), d = nb&63, s = m&2047
          vt[((size_t)((m >> 11) * 16 + (nb >> 6)) * 64 + (nb & 63)) * 2048 +
             (m & 2047)] = (bf16)val;
        } else {
          const int s = m & 2047;
          const int pi = (nb & 63) >> 1;
          const float c = ctab[s * 32 + pi];
          const float sn = stab[s * 32 + pi];
          const float part = __shfl_xor(val, 1, 64);
          float res = (nb & 1) ? fmaf(part, sn, val * c)
                               : fmaf(-part, sn, val * c);
          if (z == 0) res *= 0.18033688011112042f;  // (1/8) * log2(e)
          bf16* dst = (z == 0) ? qb : kb;
          dst[(size_t)m * 1024 + nb] = (bf16)res;
        }
      }
    }
}

// ---------------- softmax + pack for one 32x32 S^T tile (in-register) -------
// lrun accumulates PER-LANE partial sum (cross-half merge deferred to epilogue;
// valid because the rescale corr is uniform across the lane pair).
__device__ __forceinline__ void sm_pack(f32x16& s, float& mrun, float& lrun,
                                        f32x16& o0, f32x16& o1,
                                        const int sb, const int hi,
                                        unsigned* bu /*[8]*/) {
  float t0 = max3f(s[0], s[1], s[2]);
  float t1 = max3f(s[3], s[4], s[5]);
  float t2 = max3f(s[6], s[7], s[8]);
  float t3 = max3f(s[9], s[10], s[11]);
  float t4 = max3f(s[12], s[13], s[14]);
  float tm = fmaxf(max3f(t0, t1, t2), max3f(t3, t4, s[15]));
  tm = fmaxf(tm, __shfl_xor(tm, 32, 64));
  if (!__all(tm <= mrun + 8.0f)) {   // T13 defer-max
    const float mn = fmaxf(mrun, tm);
    const float corr = fexp2(mrun - mn);
    mrun = mn;
    lrun *= corr;
#pragma unroll
    for (int r = 0; r < 16; ++r) { o0[r] *= corr; o1[r] *= corr; }
  }
  float ts = 0.f;
#pragma unroll
  for (int r = 0; r < 16; ++r) {
    s[r] = fexp2(s[r] - mrun);
    ts += s[r];
  }
  lrun += ts;  // per-lane partial

  unsigned pw[8];
#pragma unroll
  for (int w = 0; w < 8; ++w) pw[w] = pkbf(s[2 * w], s[2 * w + 1]);
  unsigned rx0 = __shfl_xor(pw[sb + 0], 32, 64);
  unsigned rx1 = __shfl_xor(pw[sb + 1], 32, 64);
  unsigned rx2 = __shfl_xor(pw[4 + sb + 0], 32, 64);
  unsigned rx3 = __shfl_xor(pw[4 + sb + 1], 32, 64);
  if (hi == 0) {
    bu[0] = pw[0]; bu[1] = pw[1]; bu[2] = rx0; bu[3] = rx1;
    bu[4] = pw[4]; bu[5] = pw[5]; bu[6] = rx2; bu[7] = rx3;
  } else {
    bu[0] = rx0; bu[1] = rx1; bu[2] = pw[2]; bu[3] = pw[3];
    bu[4] = rx2; bu[5] = rx3; bu[6] = pw[6]; bu[7] = pw[7];
  }
}

// ---------------------------------------------------------------- Attention v7
// Same dataflow as v6 (PASSED), but software-pipelined within each K-tile:
// both subs' QK MFMAs issued up-front (2 independent chains), V-frag ds_reads
// prefetched under softmax VALU work, o0/o1 PV chains interleaved, lrun
// cross-half reduction deferred to the epilogue.
__global__ __launch_bounds__(128) void attn_kernel(const bf16* __restrict__ qb,
                                                   const bf16* __restrict__ kb,
                                                   const bf16* __restrict__ vt,
                                                   float* __restrict__ out) {
  __shared__ bf16 Kt[2][64][64];
  __shared__ bf16 Vt[2][64][64];

  const int tid = threadIdx.x;
  const int wid = tid >> 6;
  const int l = tid & 63;
  const int lc = l & 31;      // q index within tile (MFMA C col)
  const int hi = l >> 5;      // half-wave
  // XCD swizzle over 1024 blocks -> same-head blocks colocate per XCD
  const int bid = blockIdx.x;
  const int swz = (bid & 7) * 128 + (bid >> 3);
  const int bh = swz >> 5;          // 0..31
  const int qt = swz & 31;          // 0..31
  const int b = bh >> 4, h = bh & 15;
  const int q0 = qt * 64 + wid * 32;

  const bf16* Q = qb + (size_t)(b * 2048 + q0) * 1024 + h * 64;
  const bf16* K = kb + (size_t)(b * 2048) * 1024 + h * 64;
  const bf16* V = vt + (size_t)bh * 64 * 2048;

  // Q fragment (B-operand of QK^T): qf[md][t] = Q[q0+lc][md*16 + hi*8 + t]
  bf16x8 qf[4];
#pragma unroll
  for (int md = 0; md < 4; ++md)
    qf[md] = *reinterpret_cast<const bf16x8*>(Q + (size_t)lc * 1024 + md * 16 + hi * 8);

  // Staging: wave stages K rows [wid*32, wid*32+32) and V rows same
  const int srow = l >> 3;                  // 0..7
  const int schk = (l & 7) ^ (srow & 7);    // pre-swizzled source chunk
  const bf16* ksrc = K + (size_t)(wid * 32 + srow) * 1024 + schk * 8;
  const bf16* vsrc = V + (size_t)(wid * 32 + srow) * 2048 + schk * 8;

  f32x16 o0 = {};  // O^T rows d = 0..31  (d = (r&3)+8*(r>>2)+4*hi)
  f32x16 o1 = {};  // O^T rows d = 32..63
  float mrun = -1e30f, lrun = 0.f;
  const int sb = (hi ^ 1) * 2;  // exchange pre-select base (PROVEN form)
  const int swzk = lc & 7;      // read-side XOR key

  // prologue: stage tile 0 into buffer 0
#pragma unroll
  for (int j = 0; j < 4; ++j) {
    gload_lds16(ksrc + (size_t)8 * j * 1024, &Kt[0][wid * 32 + 8 * j][0]);
    gload_lds16(vsrc + (size_t)8 * j * 2048, &Vt[0][wid * 32 + 8 * j][0]);
  }
  __syncthreads();

  int bb = 0;
  for (int kt0 = 0; kt0 < 32; ++kt0) {
    if (kt0 < 31) {
      const size_t ko = (size_t)(kt0 + 1) * 64 * 1024;
      const size_t vo = (size_t)(kt0 + 1) * 64;
#pragma unroll
      for (int j = 0; j < 4; ++j) {
        gload_lds16(ksrc + ko + (size_t)8 * j * 1024,
                    &Kt[bb ^ 1][wid * 32 + 8 * j][0]);
        gload_lds16(vsrc + vo + (size_t)8 * j * 2048,
                    &Vt[bb ^ 1][wid * 32 + 8 * j][0]);
      }
    }

    // ---- K-fragments for BOTH subs, then QK MFMAs interleaved (2 chains)
    bf16x8 kf0[4], kf1[4];
#pragma unroll
    for (int md = 0; md < 4; ++md) {
      const int slot = (((md << 1) | hi) ^ swzk) << 3;
      kf0[md] = *reinterpret_cast<const bf16x8*>(&Kt[bb][lc][slot]);
      kf1[md] = *reinterpret_cast<const bf16x8*>(&Kt[bb][32 + lc][slot]);
    }
    f32x16 s0 = {}, s1 = {};
    __builtin_amdgcn_s_setprio(1);
#pragma unroll
    for (int md = 0; md < 4; ++md) {
      s0 = __builtin_amdgcn_mfma_f32_32x32x16_bf16(kf0[md], qf[md], s0, 0, 0, 0);
      s1 = __builtin_amdgcn_mfma_f32_32x32x16_bf16(kf1[md], qf[md], s1, 0, 0, 0);
    }
    __builtin_amdgcn_s_setprio(0);

    // ---- V-fragments for sub0 (in flight during softmax(s0))
    bf16x8 va00 = *reinterpret_cast<const bf16x8*>(&Vt[bb][lc][(hi ^ swzk) << 3]);
    bf16x8 va01 = *reinterpret_cast<const bf16x8*>(&Vt[bb][lc][((hi + 2) ^ swzk) << 3]);
    bf16x8 va10 = *reinterpret_cast<const bf16x8*>(&Vt[bb][lc + 32][(hi ^ swzk) << 3]);
    bf16x8 va11 = *reinterpret_cast<const bf16x8*>(&Vt[bb][lc + 32][((hi + 2) ^ swzk) << 3]);

    // ---- softmax + pack sub0 (QK(s1) still executing underneath)
    unsigned buA[8];
    sm_pack(s0, mrun, lrun, o0, o1, sb, hi, buA);
    union { unsigned u[4]; bf16x8 v; } A0, A1;
    A0.u[0] = buA[0]; A0.u[1] = buA[1]; A0.u[2] = buA[2]; A0.u[3] = buA[3];
    A1.u[0] = buA[4]; A1.u[1] = buA[5]; A1.u[2] = buA[6]; A1.u[3] = buA[7];

    // ---- PV sub0 (o0/o1 chains interleaved)
    __builtin_amdgcn_s_setprio(1);
    o0 = __builtin_amdgcn_mfma_f32_32x32x16_bf16(va00, A0.v, o0, 0, 0, 0);
    o1 = __builtin_amdgcn_mfma_f32_32x32x16_bf16(va10, A0.v, o1, 0, 0, 0);
    o0 = __builtin_amdgcn_mfma_f32_32x32x16_bf16(va01, A1.v, o0, 0, 0, 0);
    o1 = __builtin_amdgcn_mfma_f32_32x32x16_bf16(va11, A1.v, o1, 0, 0, 0);
    __builtin_amdgcn_s_setprio(0);

    // ---- V-fragments for sub1 (in flight during softmax(s1))
    bf16x8 vb00 = *reinterpret_cast<const bf16x8*>(&Vt[bb][lc][((4 + hi) ^ swzk) << 3]);
    bf16x8 vb01 = *reinterpret_cast<const bf16x8*>(&Vt[bb][lc][((6 + hi) ^ swzk) << 3]);
    bf16x8 vb10 = *reinterpret_cast<const bf16x8*>(&Vt[bb][lc + 32][((4 + hi) ^ swzk) << 3]);
    bf16x8 vb11 = *reinterpret_cast<const bf16x8*>(&Vt[bb][lc + 32][((6 + hi) ^ swzk) << 3]);

    // ---- softmax + pack sub1
    unsigned buB[8];
    sm_pack(s1, mrun, lrun, o0, o1, sb, hi, buB);
    union { unsigned u[4]; bf16x8 v; } B0, B1;
    B0.u[0] = buB[0]; B0.u[1] = buB[1]; B0.u[2] = buB[2]; B0.u[3] = buB[3];
    B1.u[0] = buB[4]; B1.u[1] = buB[5]; B1.u[2] = buB[6]; B1.u[3] = buB[7];

    // ---- PV sub1
    __builtin_amdgcn_s_setprio(1);
    o0 = __builtin_amdgcn_mfma_f32_32x32x16_bf16(vb00, B0.v, o0, 0, 0, 0);
    o1 = __builtin_amdgcn_mfma_f32_32x32x16_bf16(vb10, B0.v, o1, 0, 0, 0);
    o0 = __builtin_amdgcn_mfma_f32_32x32x16_bf16(vb01, B1.v, o0, 0, 0, 0);
    o1 = __builtin_amdgcn_mfma_f32_32x32x16_bf16(vb11, B1.v, o1, 0, 0, 0);
    __builtin_amdgcn_s_setprio(0);

    __syncthreads();
    bb ^= 1;
  }

  // ---- epilogue: merge per-lane lrun halves, then store O^T / lrun
  lrun += __shfl_xor(lrun, 32, 64);
  const float inv = 1.f / lrun;
  float* orow = out + (size_t)(b * 2048 + q0 + lc) * 1024 + h * 64;
#pragma unroll
  for (int g = 0; g < 4; ++g) {
    f32x4 v0, v1;
#pragma unroll
    for (int e = 0; e < 4; ++e) { v0[e] = o0[g * 4 + e] * inv; v1[e] = o1[g * 4 + e] * inv; }
    *reinterpret_cast<f32x4*>(orow + g * 8 + 4 * hi) = v0;
    *reinterpret_cast<f32x4*>(orow + 32 + g * 8 + 4 * hi) = v1;
  }
}

// ---------------------------------------------------------------- launch
extern "C" void kernel_launch(void* const* d_in, const int* in_sizes, int n_in,
                              void* d_out, int out_size, void* d_ws, size_t ws_size,
                              hipStream_t stream) {
  const float* x  = (const float*)d_in[0];
  const float* wq = (const float*)d_in[1];
  const float* bq = (const float*)d_in[2];
  const float* wk = (const float*)d_in[3];
  const float* bk = (const float*)d_in[4];
  const float* wv = (const float*)d_in[5];
  const float* bv = (const float*)d_in[6];
  float* out = (float*)d_out;

  char* ws = (char*)d_ws;
  bf16* xb  = (bf16*)(ws);                    // 8,388,608 B
  bf16* wqb = (bf16*)(ws + 8388608);          // 2,097,152
  bf16* wkb = (bf16*)(ws + 10485760);         // 2,097,152
  bf16* wvb = (bf16*)(ws + 12582912);         // 2,097,152
  bf16* qb  = (bf16*)(ws + 14680064);         // 8,388,608
  bf16* kb  = (bf16*)(ws + 23068672);         // 8,388,608
  bf16* vt  = (bf16*)(ws + 31457280);         // 8,388,608
  float* ctab = (float*)(ws + 39845888);      // 262,144
  float* stab = (float*)(ws + 40108032);      // 262,144

  prep_kernel<<<7424, 256, 0, stream>>>(x, wq, wk, wv, xb, wqb, wkb, wvb,
                                        ctab, stab);

  qkv_gemm_kernel<<<dim3(32, 8, 3), 256, 0, stream>>>(
      xb, wqb, wkb, wvb, bq, bk, bv, ctab, stab, qb, kb, vt);

  attn_kernel<<<1024, 128, 0, stream>>>(qb, kb, vt, out);
}

// Round 9
// 205.922 us; speedup vs baseline: 1.1025x; 1.0370x over previous
//
#include <hip/hip_runtime.h>

// Problem constants: B=2, S=2048, D=1024, H=16, HD=64, M = B*S = 4096

typedef __bf16 bf16;
typedef bf16  bf16x8 __attribute__((ext_vector_type(8)));
typedef bf16  bf16x4 __attribute__((ext_vector_type(4)));
typedef float f32x4  __attribute__((ext_vector_type(4)));
typedef float f32x16 __attribute__((ext_vector_type(16)));

typedef const __attribute__((address_space(1))) void* gptr_t;
typedef __attribute__((address_space(3))) void*       sptr_t;

__device__ __forceinline__ void gload_lds16(const void* g, void* l) {
  __builtin_amdgcn_global_load_lds((gptr_t)g, (sptr_t)l, 16, 0, 0);
}

__device__ __forceinline__ float fexp2(float x) {  // raw v_exp_f32 (2^x)
  float r; asm("v_exp_f32 %0, %1" : "=v"(r) : "v"(x)); return r;
}
__device__ __forceinline__ float max3f(float a, float b, float c) {
  float r; asm("v_max3_f32 %0, %1, %2, %3" : "=v"(r) : "v"(a), "v"(b), "v"(c));
  return r;
}
__device__ __forceinline__ unsigned pkbf(float a, float b) {  // lo=a, hi=b
  unsigned r;
  asm("v_cvt_pk_bf16_f32 %0, %1, %2" : "=v"(r) : "v"(a), "v"(b));
  return r;
}

// ------------------------------------------------- fused prep: f2bf x4 + rope
__global__ __launch_bounds__(256) void prep_kernel(
    const float* __restrict__ x, const float* __restrict__ wq,
    const float* __restrict__ wk, const float* __restrict__ wv,
    bf16* __restrict__ xb, bf16* __restrict__ wqb, bf16* __restrict__ wkb,
    bf16* __restrict__ wvb, float* __restrict__ ctab, float* __restrict__ stab) {
  int g = blockIdx.x * 256 + threadIdx.x;
  const float* src;
  bf16* dst;
  int i;
  if (g < 1048576) { src = x; dst = xb; i = g; }
  else if (g < 1310720) { src = wq; dst = wqb; i = g - 1048576; }
  else if (g < 1572864) { src = wk; dst = wkb; i = g - 1310720; }
  else if (g < 1835008) { src = wv; dst = wvb; i = g - 1572864; }
  else {
    int idx = g - 1835008;
    if (idx < 65536) {
      int s = idx >> 5, p = idx & 31;
      double theta = exp2(-(double)p * (13.287712379549449 / 32.0));
      double ang = (double)s * theta;
      ctab[idx] = (float)cos(ang);
      stab[idx] = (float)sin(ang);
    }
    return;
  }
  const float4 v = reinterpret_cast<const float4*>(src)[i];
  bf16x4 o;
  o[0] = (bf16)v.x; o[1] = (bf16)v.y; o[2] = (bf16)v.z; o[3] = (bf16)v.w;
  reinterpret_cast<bf16x4*>(dst)[i] = o;
}

// ---------------------------------------------------------------- QKV GEMM
// BK=64, T2 XOR-swizzled LDS (both-sides), fused RoPE epilogue; z==2 writes
// V linearly (vtrans kernel transposes afterwards — coalesced).
__global__ __launch_bounds__(256) void qkv_gemm_kernel(
    const bf16* __restrict__ xb, const bf16* __restrict__ wqb,
    const bf16* __restrict__ wkb, const bf16* __restrict__ wvb,
    const float* __restrict__ bq, const float* __restrict__ bk2,
    const float* __restrict__ bv, const float* __restrict__ ctab,
    const float* __restrict__ stab, bf16* __restrict__ qb,
    bf16* __restrict__ kb, bf16* __restrict__ vb) {
  const int z = blockIdx.z;
  const bf16* W = (z == 0) ? wqb : (z == 1) ? wkb : wvb;
  const float* bias = (z == 0) ? bq : (z == 1) ? bk2 : bv;

  __shared__ bf16 As[128 * 64];
  __shared__ bf16 Bs[128 * 64];

  const int tid = threadIdx.x;
  const int wid = tid >> 6;
  const int l = tid & 63;
  const int lg = l >> 4, lc = l & 15;
  const int wr = wid >> 1, wc = wid & 1;
  const int m0 = blockIdx.x * 128, n0 = blockIdx.y * 128;

  f32x4 acc[4][4] = {};

  const int srow = tid >> 3;                    // 0..31
  const int schunk = (tid & 7) ^ (srow & 7);    // 16B chunks, 8 per 64-col row
  const bf16* asrc = xb + (size_t)(m0 + srow) * 1024 + schunk * 8;
  const bf16* bsrc = W + (size_t)(n0 + srow) * 1024 + schunk * 8;
  char* alds = (char*)As + wid * 1024;
  char* blds = (char*)Bs + wid * 1024;

  for (int k0 = 0; k0 < 1024; k0 += 64) {
#pragma unroll
    for (int i = 0; i < 4; ++i) {
      gload_lds16(asrc + (size_t)32 * i * 1024 + k0, alds + i * 4096);
      gload_lds16(bsrc + (size_t)32 * i * 1024 + k0, blds + i * 4096);
    }
    __syncthreads();
    bf16x8 af[4][2], bfr[4][2];
#pragma unroll
    for (int i = 0; i < 4; ++i) {
      const int row = wr * 64 + i * 16 + lc;
#pragma unroll
      for (int h = 0; h < 2; ++h) {
        const int slot = (h * 4 + lg) ^ (row & 7);
        af[i][h] = *reinterpret_cast<const bf16x8*>(
            (const char*)As + row * 128 + slot * 16);
      }
    }
#pragma unroll
    for (int j = 0; j < 4; ++j) {
      const int row = wc * 64 + j * 16 + lc;
#pragma unroll
      for (int h = 0; h < 2; ++h) {
        const int slot = (h * 4 + lg) ^ (row & 7);
        bfr[j][h] = *reinterpret_cast<const bf16x8*>(
            (const char*)Bs + row * 128 + slot * 16);
      }
    }
    __builtin_amdgcn_s_setprio(1);
#pragma unroll
    for (int i = 0; i < 4; ++i)
#pragma unroll
      for (int j = 0; j < 4; ++j) {
        acc[i][j] = __builtin_amdgcn_mfma_f32_16x16x32_bf16(af[i][0], bfr[j][0],
                                                            acc[i][j], 0, 0, 0);
        acc[i][j] = __builtin_amdgcn_mfma_f32_16x16x32_bf16(af[i][1], bfr[j][1],
                                                            acc[i][j], 0, 0, 0);
      }
    __builtin_amdgcn_s_setprio(0);
    __syncthreads();
  }

#pragma unroll
  for (int i = 0; i < 4; ++i)
#pragma unroll
    for (int j = 0; j < 4; ++j) {
      const int nb = n0 + wc * 64 + j * 16 + lc;
      const float bval = bias[nb];
#pragma unroll
      for (int r = 0; r < 4; ++r) {
        const int m = m0 + wr * 64 + i * 16 + lg * 4 + r;
        const float val = acc[i][j][r] + bval;
        if (z == 2) {
          vb[(size_t)m * 1024 + nb] = (bf16)val;
        } else {
          const int s = m & 2047;
          const int pi = (nb & 63) >> 1;
          const float c = ctab[s * 32 + pi];
          const float sn = stab[s * 32 + pi];
          const float part = __shfl_xor(val, 1, 64);
          float res = (nb & 1) ? fmaf(part, sn, val * c)
                               : fmaf(-part, sn, val * c);
          if (z == 0) res *= 0.18033688011112042f;  // (1/8) * log2(e)
          bf16* dst = (z == 0) ? qb : kb;
          dst[(size_t)m * 1024 + nb] = (bf16)res;
        }
      }
    }
}

// ---------------------------------------------------------------- V transpose
// vb [4096][1024] -> vt [bh=32][hd=64][s=2048]   (R4-proven, coalesced)
__global__ __launch_bounds__(256) void vtrans_kernel(const bf16* __restrict__ vb,
                                                     bf16* __restrict__ vt) {
  __shared__ bf16 tile[64][65];
  const int bh = blockIdx.y, b = bh >> 4, h = bh & 15;
  const int s0 = blockIdx.x * 64;
  const int t = threadIdx.x;
#pragma unroll
  for (int idx = t; idx < 4096; idx += 256) {
    int r = idx >> 6, c = idx & 63;
    tile[r][c] = vb[(size_t)(b * 2048 + s0 + r) * 1024 + h * 64 + c];
  }
  __syncthreads();
#pragma unroll
  for (int idx = t; idx < 4096; idx += 256) {
    int d = idx >> 6, r = idx & 63;
    vt[(size_t)(bh * 64 + d) * 2048 + s0 + r] = tile[r][d];
  }
}

// ---------------- softmax + pack for one 32x32 S^T tile (in-register) -------
// lrun accumulates PER-LANE partial sum (cross-half merge deferred).
__device__ __forceinline__ void sm_pack(f32x16& s, float& mrun, float& lrun,
                                        f32x16& o0, f32x16& o1,
                                        const int sb, const int hi,
                                        unsigned* bu /*[8]*/) {
  float t0 = max3f(s[0], s[1], s[2]);
  float t1 = max3f(s[3], s[4], s[5]);
  float t2 = max3f(s[6], s[7], s[8]);
  float t3 = max3f(s[9], s[10], s[11]);
  float t4 = max3f(s[12], s[13], s[14]);
  float tm = fmaxf(max3f(t0, t1, t2), max3f(t3, t4, s[15]));
  tm = fmaxf(tm, __shfl_xor(tm, 32, 64));
  if (!__all(tm <= mrun + 8.0f)) {   // T13 defer-max
    const float mn = fmaxf(mrun, tm);
    const float corr = fexp2(mrun - mn);
    mrun = mn;
    lrun *= corr;
#pragma unroll
    for (int r = 0; r < 16; ++r) { o0[r] *= corr; o1[r] *= corr; }
  }
  float ts = 0.f;
#pragma unroll
  for (int r = 0; r < 16; ++r) {
    s[r] = fexp2(s[r] - mrun);
    ts += s[r];
  }
  lrun += ts;  // per-lane partial

  unsigned pw[8];
#pragma unroll
  for (int w = 0; w < 8; ++w) pw[w] = pkbf(s[2 * w], s[2 * w + 1]);
  unsigned rx0 = __shfl_xor(pw[sb + 0], 32, 64);
  unsigned rx1 = __shfl_xor(pw[sb + 1], 32, 64);
  unsigned rx2 = __shfl_xor(pw[4 + sb + 0], 32, 64);
  unsigned rx3 = __shfl_xor(pw[4 + sb + 1], 32, 64);
  if (hi == 0) {
    bu[0] = pw[0]; bu[1] = pw[1]; bu[2] = rx0; bu[3] = rx1;
    bu[4] = pw[4]; bu[5] = pw[5]; bu[6] = rx2; bu[7] = rx3;
  } else {
    bu[0] = rx0; bu[1] = rx1; bu[2] = pw[2]; bu[3] = pw[3];
    bu[4] = rx2; bu[5] = rx3; bu[6] = pw[6]; bu[7] = pw[7];
  }
}

// ---------------------------------------------------------------- Attention v8
// 4 waves = 2 q-tiles x 2 kv-halves. Each kv-half sweeps 1024 kv in 32-row
// tiles (dbuf). LDS rows interleave both halves (128B/256B rows keep the XOR
// swizzle). End-of-kernel merge across kv-halves via LDS.
__global__ __launch_bounds__(256, 4) void attn_kernel(
    const bf16* __restrict__ qb, const bf16* __restrict__ kb,
    const bf16* __restrict__ vt, float* __restrict__ out) {
  // K: [buf][32 row][2 half][64 d]  = 16 KB  (256B rows)
  // V: [buf][64 d ][2 half][32 kv] = 16 KB  (128B rows)
  __shared__ bf16 Klds[2][32][128];
  __shared__ bf16 Vlds[2][64][64];

  const int tid = threadIdx.x;
  const int wid = tid >> 6;
  const int l = tid & 63;
  const int lc = l & 31;      // q index (MFMA C col)
  const int hi = l >> 5;      // half-wave
  const int qw = wid & 1;     // q-tile within block
  const int kvh = wid >> 1;   // kv half
  // XCD swizzle over 1024 blocks
  const int bid = blockIdx.x;
  const int swz = (bid & 7) * 128 + (bid >> 3);
  const int bh = swz >> 5;          // 0..31
  const int qt = swz & 31;          // 0..31
  const int b = bh >> 4, h = bh & 15;
  const int q0 = qt * 64 + qw * 32;

  const bf16* Q = qb + (size_t)(b * 2048 + q0) * 1024 + h * 64;
  const bf16* Kbase = kb + (size_t)(b * 2048) * 1024 + h * 64;
  const bf16* Vbase = vt + (size_t)bh * 64 * 2048;

  // Q fragment: qf[md][t] = Q[q0+lc][md*16 + hi*8 + t]
  bf16x8 qf[4];
#pragma unroll
  for (int md = 0; md < 4; ++md)
    qf[md] = *reinterpret_cast<const bf16x8*>(Q + (size_t)lc * 1024 + md * 16 + hi * 8);

  // ---- staging source pointers (per-lane constant; advance by t)
  // K gloads: g = wid*2+j covers local rows g*4..g*4+3 (256B each).
  //   lane offset o = l*16: row = g*4 + (o>>8); halfL = (o>>7)&1; chunk=(o>>4)&7
  //   src chunk pre-swizzled: chunk ^ (row&7)
  const int o16 = l * 16;
  const bf16* ksrc[2];
  const bf16* vsrc[2];
#pragma unroll
  for (int j = 0; j < 2; ++j) {
    const int gk = wid * 2 + j;
    const int krow = gk * 4 + (o16 >> 8);
    const int khalf = (o16 >> 7) & 1;
    const int kchunk = ((o16 >> 4) & 7) ^ (krow & 7);
    ksrc[j] = Kbase + (size_t)(khalf * 1024 + krow) * 1024 + kchunk * 8;
    // V gloads: g covers d rows g*8..g*8+7 (128B each).
    //   d = g*8 + (o>>7); phys = (o>>4)&7; logical = phys ^ (d&7);
    //   halfL = logical>>2; cc = logical&3
    const int d = gk * 8 + (o16 >> 7);
    const int vlog = ((o16 >> 4) & 7) ^ (d & 7);
    vsrc[j] = Vbase + (size_t)d * 2048 + (vlog >> 2) * 1024 + (vlog & 3) * 8;
  }

  f32x16 o0 = {};  // O^T rows d = 0..31  (d = (r&3)+8*(r>>2)+4*hi)
  f32x16 o1 = {};  // O^T rows d = 32..63
  float mrun = -1e30f, lrun = 0.f;
  const int sb = (hi ^ 1) * 2;  // exchange pre-select base (PROVEN)
  const int swzk = lc & 7;      // K read-side XOR key

  // prologue: stage tile 0 into buffer 0
#pragma unroll
  for (int j = 0; j < 2; ++j) {
    const int gk = wid * 2 + j;
    gload_lds16(ksrc[j], &Klds[0][gk * 4][0]);
    gload_lds16(vsrc[j], &Vlds[0][gk * 8][0]);
  }
  __syncthreads();

  int bb = 0;
  for (int t = 0; t < 32; ++t) {
    if (t < 31) {
      const size_t ko = (size_t)(t + 1) * 32 * 1024;  // +32 kv rows
      const size_t vo = (size_t)(t + 1) * 32;         // +32 kv cols
#pragma unroll
      for (int j = 0; j < 2; ++j) {
        const int gk = wid * 2 + j;
        gload_lds16(ksrc[j] + ko, &Klds[bb ^ 1][gk * 4][0]);
        gload_lds16(vsrc[j] + vo, &Vlds[bb ^ 1][gk * 8][0]);
      }
    }

    // ---- QK: S^T tile [32 k][32 q] for this kv-half
    f32x16 s = {};
    __builtin_amdgcn_s_setprio(1);
#pragma unroll
    for (int md = 0; md < 4; ++md) {
      const int slot = (((md << 1) | hi) ^ swzk);
      bf16x8 kf = *reinterpret_cast<const bf16x8*>(
          &Klds[bb][lc][kvh * 64 + slot * 8]);
      s = __builtin_amdgcn_mfma_f32_32x32x16_bf16(kf, qf[md], s, 0, 0, 0);
    }
    __builtin_amdgcn_s_setprio(0);

    // ---- V fragments (physical chunk = (kvh*4 + cc) ^ (d&7))
    const int c0 = (kvh * 4 + hi);
    const int c1 = (kvh * 4 + 2 + hi);
    bf16x8 va00 = *reinterpret_cast<const bf16x8*>(
        &Vlds[bb][lc][(c0 ^ (lc & 7)) * 8]);
    bf16x8 va01 = *reinterpret_cast<const bf16x8*>(
        &Vlds[bb][lc][(c1 ^ (lc & 7)) * 8]);
    bf16x8 va10 = *reinterpret_cast<const bf16x8*>(
        &Vlds[bb][lc + 32][(c0 ^ ((lc + 32) & 7)) * 8]);
    bf16x8 va11 = *reinterpret_cast<const bf16x8*>(
        &Vlds[bb][lc + 32][(c1 ^ ((lc + 32) & 7)) * 8]);

    // ---- softmax + pack (in-register)
    unsigned bu[8];
    sm_pack(s, mrun, lrun, o0, o1, sb, hi, bu);
    union { unsigned u[4]; bf16x8 v; } A0, A1;
    A0.u[0] = bu[0]; A0.u[1] = bu[1]; A0.u[2] = bu[2]; A0.u[3] = bu[3];
    A1.u[0] = bu[4]; A1.u[1] = bu[5]; A1.u[2] = bu[6]; A1.u[3] = bu[7];

    // ---- PV (k = 32: A0 covers k 0..15, A1 k 16..31)
    __builtin_amdgcn_s_setprio(1);
    o0 = __builtin_amdgcn_mfma_f32_32x32x16_bf16(va00, A0.v, o0, 0, 0, 0);
    o1 = __builtin_amdgcn_mfma_f32_32x32x16_bf16(va10, A0.v, o1, 0, 0, 0);
    o0 = __builtin_amdgcn_mfma_f32_32x32x16_bf16(va01, A1.v, o0, 0, 0, 0);
    o1 = __builtin_amdgcn_mfma_f32_32x32x16_bf16(va11, A1.v, o1, 0, 0, 0);
    __builtin_amdgcn_s_setprio(0);

    __syncthreads();
    bb ^= 1;
  }

  // ---- merge across kv-halves (waves kvh=1 publish; kvh=0 merge+store)
  // o0+m+l in K region (2*64*18*4 = 9216 B), o1 in V region (8192 B).
  float* c0lds = (float*)&Klds[0][0][0];
  float* c1lds = (float*)&Vlds[0][0][0];
  if (kvh == 1) {
    float* d0 = c0lds + (qw * 64 + l) * 18;
    float* d1 = c1lds + (qw * 64 + l) * 16;
#pragma unroll
    for (int r = 0; r < 16; ++r) { d0[r] = o0[r]; d1[r] = o1[r]; }
    d0[16] = mrun; d0[17] = lrun;
  }
  __syncthreads();
  if (kvh == 0) {
    const float* s0 = c0lds + (qw * 64 + l) * 18;
    const float* s1 = c1lds + (qw * 64 + l) * 16;
    const float mb = s0[16], lb = s0[17];
    const float M = fmaxf(mrun, mb);
    const float ca = fexp2(mrun - M), cb = fexp2(mb - M);
    lrun = lrun * ca + lb * cb;
    lrun += __shfl_xor(lrun, 32, 64);  // cross-half-of-wave final sum
    const float inv = 1.f / lrun;
    float* orow = out + (size_t)(b * 2048 + q0 + lc) * 1024 + h * 64;
#pragma unroll
    for (int g = 0; g < 4; ++g) {
      f32x4 v0, v1;
#pragma unroll
      for (int e = 0; e < 4; ++e) {
        v0[e] = (o0[g * 4 + e] * ca + s0[g * 4 + e] * cb) * inv;
        v1[e] = (o1[g * 4 + e] * ca + s1[g * 4 + e] * cb) * inv;
      }
      *reinterpret_cast<f32x4*>(orow + g * 8 + 4 * hi) = v0;
      *reinterpret_cast<f32x4*>(orow + 32 + g * 8 + 4 * hi) = v1;
    }
  }
}

// ---------------------------------------------------------------- launch
extern "C" void kernel_launch(void* const* d_in, const int* in_sizes, int n_in,
                              void* d_out, int out_size, void* d_ws, size_t ws_size,
                              hipStream_t stream) {
  const float* x  = (const float*)d_in[0];
  const float* wq = (const float*)d_in[1];
  const float* bq = (const float*)d_in[2];
  const float* wk = (const float*)d_in[3];
  const float* bk = (const float*)d_in[4];
  const float* wv = (const float*)d_in[5];
  const float* bv = (const float*)d_in[6];
  float* out = (float*)d_out;

  char* ws = (char*)d_ws;
  bf16* xb  = (bf16*)(ws);                    // 8,388,608 B
  bf16* wqb = (bf16*)(ws + 8388608);          // 2,097,152
  bf16* wkb = (bf16*)(ws + 10485760);         // 2,097,152
  bf16* wvb = (bf16*)(ws + 12582912);         // 2,097,152
  bf16* qb  = (bf16*)(ws + 14680064);         // 8,388,608
  bf16* kb  = (bf16*)(ws + 23068672);         // 8,388,608
  bf16* vb  = (bf16*)(ws + 31457280);         // 8,388,608
  bf16* vt  = (bf16*)(ws + 39845888);         // 8,388,608
  float* ctab = (float*)(ws + 48234496);      // 262,144
  float* stab = (float*)(ws + 48496640);      // 262,144

  prep_kernel<<<7424, 256, 0, stream>>>(x, wq, wk, wv, xb, wqb, wkb, wvb,
                                        ctab, stab);

  qkv_gemm_kernel<<<dim3(32, 8, 3), 256, 0, stream>>>(
      xb, wqb, wkb, wvb, bq, bk, bv, ctab, stab, qb, kb, vb);

  vtrans_kernel<<<dim3(32, 32), 256, 0, stream>>>(vb, vt);

  attn_kernel<<<1024, 256, 0, stream>>>(qb, kb, vt, out);
}